// Round 5
// baseline (13.381 us; speedup 1.0000x reference)
//
#include <hip/hip_runtime.h>

// MiniBatchAUC: loss = sum_{i in pos, j in neg} (1 - (s_i - s_j))^2 / (n_pos*n_neg),
// s = sigmoid(logits). Closed form via O(N) sufficient statistics:
//   np, Sp, Sp2, S, S2;  nn = N-np, Sn = S-Sp, Sn2 = S2-Sp2
//   loss_total = np*nn - 2*nn*Sp + 2*np*Sn + nn*Sp2 + np*Sn2 - 2*Sp*Sn
//
// R1/R4: 1 block, 1 dispatch = 10.43 us (kernel ~1.5 us single-CU-bound).
// R2: +1 dispatch = +0.8 us. R3: cooperative grid.sync = +21 us. => Stay at
// ONE plain dispatch but spread loads over 64 CUs with a flag-based
// producer->consumer handoff inside the dispatch:
//   - 64 blocks x 64 threads: one float4+int4 per lane (2 KB per CU).
//   - lane 0 of each block publishes 5 partials + 2 MAGIC words via
//     device-scope (L2) atomics (release-ordered).
//   - block 0 polls the 64 flag pairs, then butterfly-combines in double.
// No reset needed across replays: partials are deterministic, so stale
// flags/partials from the previous replay are value-identical; harness poison
// (0xAAAAAAAA) != MAGIC, so within-epoch validity is correctly signaled.

#define GRID 64
#define BLK  64
#define MAGIC1 0x5F3759DFu
#define MAGIC2 0x9E3779B9u

__global__ __launch_bounds__(BLK) void auc_onepass_kernel(
    const float* __restrict__ logits, const int* __restrict__ targets,
    unsigned* __restrict__ ws, float* __restrict__ out, int n) {
  const int tid  = threadIdx.x;
  const int bid  = blockIdx.x;
  const int gtid = bid * BLK + tid;
  const int nthreads = GRID * BLK;

  // acc: [0]=np [1]=Sp [2]=Sp2 [3]=S [4]=S2
  float acc[5] = {0.f, 0.f, 0.f, 0.f, 0.f};

  const int n4 = n >> 2;
  const float4* l4 = reinterpret_cast<const float4*>(logits);
  const int4*   t4 = reinterpret_cast<const int4*>(targets);

  for (int i = gtid; i < n4; i += nthreads) {  // exactly one iter at N=16384
    float4 lv = l4[i];
    int4   tv = t4[i];
    float xs[4] = {lv.x, lv.y, lv.z, lv.w};
    int   ts[4] = {tv.x, tv.y, tv.z, tv.w};
#pragma unroll
    for (int k = 0; k < 4; ++k) {
      float s  = 1.0f / (1.0f + __expf(-xs[k]));
      float s2 = s * s;
      float p  = (ts[k] != 0) ? 1.0f : 0.0f;  // predicated, no divergence
      acc[0] += p;
      acc[1] += p * s;
      acc[2] += p * s2;
      acc[3] += s;
      acc[4] += s2;
    }
  }
  // scalar tail for n % 4 != 0 (not hit at N=16384)
  for (int i = (n4 << 2) + gtid; i < n; i += nthreads) {
    float s  = 1.0f / (1.0f + __expf(-logits[i]));
    float s2 = s * s;
    float p  = (targets[i] != 0) ? 1.0f : 0.0f;
    acc[0] += p;
    acc[1] += p * s;
    acc[2] += p * s2;
    acc[3] += s;
    acc[4] += s2;
  }

  // wave-64 butterfly reduce (block == one wave); all lanes end with block sum
#pragma unroll
  for (int j = 0; j < 5; ++j) {
#pragma unroll
    for (int m = 1; m < 64; m <<= 1) {
      acc[j] += __shfl_xor(acc[j], m, 64);
    }
  }

  // producer: lane 0 publishes partials then flags (release), L2-scope
  unsigned* slot = ws + bid * 8;
  if (tid == 0) {
#pragma unroll
    for (int j = 0; j < 5; ++j)
      __hip_atomic_store(&slot[j], __float_as_uint(acc[j]),
                         __ATOMIC_RELAXED, __HIP_MEMORY_SCOPE_AGENT);
    __hip_atomic_store(&slot[5], MAGIC1, __ATOMIC_RELEASE, __HIP_MEMORY_SCOPE_AGENT);
    __hip_atomic_store(&slot[6], MAGIC2, __ATOMIC_RELEASE, __HIP_MEMORY_SCOPE_AGENT);
  }

  if (bid != 0) return;

  // consumer: lane g owns block g's slot (GRID == BLK == 64)
  unsigned* ps = ws + tid * 8;
  for (;;) {
    unsigned f1 = __hip_atomic_load(&ps[5], __ATOMIC_ACQUIRE, __HIP_MEMORY_SCOPE_AGENT);
    unsigned f2 = __hip_atomic_load(&ps[6], __ATOMIC_ACQUIRE, __HIP_MEMORY_SCOPE_AGENT);
    if (f1 == MAGIC1 && f2 == MAGIC2) break;
    __builtin_amdgcn_s_sleep(1);
  }

  double t[5];
#pragma unroll
  for (int j = 0; j < 5; ++j)
    t[j] = (double)__uint_as_float(
        __hip_atomic_load(&ps[j], __ATOMIC_RELAXED, __HIP_MEMORY_SCOPE_AGENT));

  // butterfly combine in double across 64 lanes (fixed order -> deterministic)
#pragma unroll
  for (int j = 0; j < 5; ++j) {
#pragma unroll
    for (int m = 1; m < 64; m <<= 1) {
      t[j] += __shfl_xor(t[j], m, 64);
    }
  }

  if (tid == 0) {
    double np_ = t[0], sp = t[1], sp2 = t[2], S = t[3], S2 = t[4];
    double nn  = (double)n - np_;
    double sn  = S - sp;
    double sn2 = S2 - sp2;
    double loss = np_ * nn
                - 2.0 * nn * sp
                + 2.0 * np_ * sn
                + nn * sp2
                + np_ * sn2
                - 2.0 * sp * sn;
    out[0] = (float)(loss / (np_ * nn));
  }
}

extern "C" void kernel_launch(void* const* d_in, const int* in_sizes, int n_in,
                              void* d_out, int out_size, void* d_ws, size_t ws_size,
                              hipStream_t stream) {
  const float* logits  = (const float*)d_in[0];
  const int*   targets = (const int*)d_in[1];
  float*       out     = (float*)d_out;
  unsigned*    ws      = (unsigned*)d_ws;   // needs GRID*8 u32 = 2 KB
  const int n = in_sizes[0];

  auc_onepass_kernel<<<dim3(GRID), dim3(BLK), 0, stream>>>(logits, targets, ws, out, n);
}

// Round 6
// 10.469 us; speedup vs baseline: 1.2782x; 1.2782x over previous
//
#include <hip/hip_runtime.h>

// MiniBatchAUC: loss = sum_{i in pos, j in neg} (1 - (s_i - s_j))^2 / (n_pos*n_neg),
// s = sigmoid(logits). Closed form via O(N) sufficient statistics:
//   np, Sp = sum_pos s, Sp2 = sum_pos s^2, S = sum s, S2 = sum s^2
//   nn = N-np, Sn = S-Sp, Sn2 = S2-Sp2
//   loss_total = np*nn - 2*nn*Sp + 2*np*Sn + nn*Sp2 + np*Sn2 - 2*Sp*Sn
//
// Round history (measured):
//   R1  1 block, 1 dispatch                 10.77 us
//   R2  2 dispatches (partial+combine)      11.26 us  (+0.8 us for 2nd dispatch)
//   R3  cooperative grid.sync               32.27 us  (grid.sync ~ +21 us)
//   R4  1 block, 5 stats (this kernel)      10.43 us  <- best
//   R5  64-block flag handoff in-dispatch   13.38 us  (L2 flag round-trip > gain;
//                                                      22.7 ms under rocprof replay)
// Model: dur_us = ~9 us fixed graph-replay/launch overhead + ~1.4 us kernel
// (128 KB through one CU's L1). All cross-block schemes cost more than the
// single-CU serialization they remove. This is the launch-overhead floor.

#define BLOCK 1024

__global__ __launch_bounds__(BLOCK) void auc_stats_kernel(
    const float* __restrict__ logits, const int* __restrict__ targets,
    float* __restrict__ out, int n) {
  const int tid = threadIdx.x;

  // acc: [0]=np [1]=Sp [2]=Sp2 [3]=S [4]=S2
  float acc[5] = {0.f, 0.f, 0.f, 0.f, 0.f};

  const int n4 = n >> 2;
  const float4* l4 = reinterpret_cast<const float4*>(logits);
  const int4*   t4 = reinterpret_cast<const int4*>(targets);

  for (int i = tid; i < n4; i += BLOCK) {
    float4 lv = l4[i];
    int4   tv = t4[i];
    float xs[4] = {lv.x, lv.y, lv.z, lv.w};
    int   ts[4] = {tv.x, tv.y, tv.z, tv.w};
#pragma unroll
    for (int k = 0; k < 4; ++k) {
      float s  = 1.0f / (1.0f + __expf(-xs[k]));
      float s2 = s * s;
      float p  = (ts[k] != 0) ? 1.0f : 0.0f;  // predicated, no divergence
      acc[0] += p;
      acc[1] += p * s;
      acc[2] += p * s2;
      acc[3] += s;
      acc[4] += s2;
    }
  }
  // scalar tail for n % 4 != 0 (not hit at N=16384)
  for (int i = (n4 << 2) + tid; i < n; i += BLOCK) {
    float s  = 1.0f / (1.0f + __expf(-logits[i]));
    float s2 = s * s;
    float p  = (targets[i] != 0) ? 1.0f : 0.0f;
    acc[0] += p;
    acc[1] += p * s;
    acc[2] += p * s2;
    acc[3] += s;
    acc[4] += s2;
  }

  // wave-64 butterfly reduce
#pragma unroll
  for (int j = 0; j < 5; ++j) {
#pragma unroll
    for (int m = 1; m < 64; m <<= 1) {
      acc[j] += __shfl_xor(acc[j], m, 64);
    }
  }

  __shared__ float lds[BLOCK / 64][5];
  const int wave = tid >> 6;
  const int lane = tid & 63;
  if (lane == 0) {
#pragma unroll
    for (int j = 0; j < 5; ++j) lds[wave][j] = acc[j];
  }
  __syncthreads();

  if (tid == 0) {
    double t[5] = {0, 0, 0, 0, 0};
    for (int w = 0; w < BLOCK / 64; ++w)
      for (int j = 0; j < 5; ++j) t[j] += (double)lds[w][j];

    double np_ = t[0], sp = t[1], sp2 = t[2], S = t[3], S2 = t[4];
    double nn  = (double)n - np_;
    double sn  = S - sp;
    double sn2 = S2 - sp2;
    double loss = np_ * nn
                - 2.0 * nn * sp
                + 2.0 * np_ * sn
                + nn * sp2
                + np_ * sn2
                - 2.0 * sp * sn;
    out[0] = (float)(loss / (np_ * nn));
  }
}

extern "C" void kernel_launch(void* const* d_in, const int* in_sizes, int n_in,
                              void* d_out, int out_size, void* d_ws, size_t ws_size,
                              hipStream_t stream) {
  const float* logits  = (const float*)d_in[0];
  const int*   targets = (const int*)d_in[1];
  float*       out     = (float*)d_out;
  const int n = in_sizes[0];

  auc_stats_kernel<<<dim3(1), dim3(BLOCK), 0, stream>>>(logits, targets, out, n);
}